// Round 10
// baseline (4261.292 us; speedup 1.0000x reference)
//
#include <hip/hip_runtime.h>
#include <hip/hip_bf16.h>

// LSTM forward: T=512 (511 steps), B=1024, I=128, H=256, 4H=1024.
// Round 5d: structural redesign, proven sc0+sc1 coherence, short guard.
//  * All cross-wg traffic: sc0 sc1 (agent/MALL coherent) — identical ordering
//    semantics to the baseline's relaxed agent-scope atomics, which passed.
//    (Round 7 showed sc0-only is NOT coherent across CUs on gfx950.)
//  * W_hh fragments register-resident (16 bf16x8/lane) -> zero LDS use in
//    the loop, no barriers; removes 1.0e8 LDS bank-conflict cycles and
//    16 ds_read_b128 per wave per step.
//  * h exchanged directly global<->MFMA-fragment (no LDS staging hop, no
//    __syncthreads; waves pipeline independently).
//  * per-wave u16 flag slots (plain stores + __all poll) replace 32
//    serialized fetch_adds on one cacheline.
//  * guard = 1<<16 (~20 ms worst case): fail-fast with readable absmax
//    instead of wedging the container if the handshake ever breaks.

#define T_STEPS 511
#define BATCH   1024
#define IN      128
#define HID     256
#define NG      1024
#define KTOT    384
#define BWG     16
#define NGROUP  64

typedef __bf16 bf16x8 __attribute__((ext_vector_type(8)));
typedef float  f32x4  __attribute__((ext_vector_type(4)));
typedef unsigned int u32x4 __attribute__((ext_vector_type(4)));
typedef unsigned long long u64;

// workspace layout (bytes)
#define WCAT_OFF 0
#define BIAS_OFF 786432
#define HEXG_OFF 790528                 // 2*64*16*256 bf16 = 1 MB
#define CNT_OFF  1839104                // u16 flags[64][32] (4KB)

__global__ void precast_kernel(const float* __restrict__ W_ih,
                               const float* __restrict__ W_hh,
                               const float* __restrict__ b_ih,
                               const float* __restrict__ b_hh,
                               __bf16* __restrict__ wcat,
                               float* __restrict__ bias,
                               int* __restrict__ cnt) {
    int idx = blockIdx.x * blockDim.x + threadIdx.x;
    if (idx < NG * KTOT) {
        int n = idx / KTOT, k = idx % KTOT;
        float v = (k < IN) ? W_ih[n * IN + k] : W_hh[n * HID + (k - IN)];
        wcat[idx] = (__bf16)v;
    }
    if (idx < NG) bias[idx] = b_ih[idx] + b_hh[idx];
    if (idx < NGROUP * 32) cnt[idx] = 0;   // zeroes flags (4KB) + slack
}

__device__ __forceinline__ float sigmoidf_fast(float v) {
    return 1.f / (1.f + __expf(-v));
}
__device__ __forceinline__ float tanhf_fast(float v) {
    return 1.f - 2.f / (1.f + __expf(2.f * v));
}

#define MFMA(a, b, c) __builtin_amdgcn_mfma_f32_16x16x32_bf16((a), (b), (c), 0, 0, 0)

__device__ __forceinline__ bf16x8 cvt_pack(float4 lo, float4 hi) {
    return bf16x8{(__bf16)lo.x, (__bf16)lo.y, (__bf16)lo.z, (__bf16)lo.w,
                  (__bf16)hi.x, (__bf16)hi.y, (__bf16)hi.z, (__bf16)hi.w};
}

// ---- cross-wg memory primitives: sc0 sc1 (MALL-coherent, proven) ---------

__device__ __forceinline__ unsigned ld_u16_coh(const unsigned short* p) {
    unsigned v;
    asm volatile("global_load_ushort %0, %1, off sc0 sc1\n\t"
                 "s_waitcnt vmcnt(0)"
                 : "=&v"(v) : "v"(p) : "memory");
    return v;
}

__device__ __forceinline__ void st_u32_coh(unsigned* p, unsigned v) {
    asm volatile("global_store_dword %0, %1, off sc0 sc1" :: "v"(p), "v"(v) : "memory");
}

__device__ __forceinline__ void st_u16_coh(unsigned short* p, unsigned v) {
    asm volatile("global_store_short %0, %1, off sc0 sc1" :: "v"(p), "v"(v) : "memory");
}

// 8 x dwordx4: one full 16x256 h-tile row-fragment set per lane.
// waitcnt lives INSIDE the asm; consumers depend on the outputs.
// gfx950 asm modifier order: offset:N BEFORE sc0/sc1.
__device__ __forceinline__ void ld_hfrag(bf16x8 (&a)[8], const __bf16* base) {
    u32x4 t0, t1, t2, t3, t4, t5, t6, t7;
    asm volatile(
        "global_load_dwordx4 %0, %8, off sc0 sc1\n\t"
        "global_load_dwordx4 %1, %8, off offset:64 sc0 sc1\n\t"
        "global_load_dwordx4 %2, %8, off offset:128 sc0 sc1\n\t"
        "global_load_dwordx4 %3, %8, off offset:192 sc0 sc1\n\t"
        "global_load_dwordx4 %4, %8, off offset:256 sc0 sc1\n\t"
        "global_load_dwordx4 %5, %8, off offset:320 sc0 sc1\n\t"
        "global_load_dwordx4 %6, %8, off offset:384 sc0 sc1\n\t"
        "global_load_dwordx4 %7, %8, off offset:448 sc0 sc1\n\t"
        "s_waitcnt vmcnt(0)"
        : "=&v"(t0), "=&v"(t1), "=&v"(t2), "=&v"(t3),
          "=&v"(t4), "=&v"(t5), "=&v"(t6), "=&v"(t7)
        : "v"(base) : "memory");
    a[0] = __builtin_bit_cast(bf16x8, t0);
    a[1] = __builtin_bit_cast(bf16x8, t1);
    a[2] = __builtin_bit_cast(bf16x8, t2);
    a[3] = __builtin_bit_cast(bf16x8, t3);
    a[4] = __builtin_bit_cast(bf16x8, t4);
    a[5] = __builtin_bit_cast(bf16x8, t5);
    a[6] = __builtin_bit_cast(bf16x8, t6);
    a[7] = __builtin_bit_cast(bf16x8, t7);
}

__global__ __launch_bounds__(512, 2) void lstm_kernel(
    const float* __restrict__ x,      // (512,1024,128) fp32
    const __bf16* __restrict__ wcat,  // (1024,384) bf16
    const float* __restrict__ bias,   // (1024,)
    const float* __restrict__ hx0,
    const float* __restrict__ cx0,
    __bf16* __restrict__ hexg,        // [2][64][16][256] bf16
    int* __restrict__ cnt,            // flags region
    float* __restrict__ out)          // h (1024,256), c (1024,256) fp32
{
    const int tid  = threadIdx.x;
    const int bx   = blockIdx.x;
    const int g    = bx & 63;          // batch group 0..63
    const int s    = bx >> 6;          // hidden slice 0..3
    const int wave = tid >> 6;
    const int lane = tid & 63;
    const int col  = lane & 15;
    const int quad = lane >> 4;
    const int hf   = col >> 3;         // 0: {i,g} lanes, 1: {f,o} lanes
    const int b0   = g * BWG;
    const int j0   = s * 64;
    const int jcol = j0 + wave * 8 + (col & 7);

    unsigned short* flags = (unsigned short*)cnt;        // [64][32] u16

    // ---- loop-invariant weight fragments in registers ----
    const int n0 = (hf ? 256 : 0) + jcol;
    const int n1 = 512 + (hf ? 256 : 0) + jcol;
    bf16x8 wi0[4], wi1[4], wh0[8], wh1[8];
    #pragma unroll
    for (int ks = 0; ks < 4; ++ks) {
        wi0[ks] = *(const bf16x8*)(wcat + (size_t)n0 * KTOT + ks * 32 + quad * 8);
        wi1[ks] = *(const bf16x8*)(wcat + (size_t)n1 * KTOT + ks * 32 + quad * 8);
    }
    #pragma unroll
    for (int ks = 0; ks < 8; ++ks) {
        wh0[ks] = *(const bf16x8*)(wcat + (size_t)n0 * KTOT + IN + ks * 32 + quad * 8);
        wh1[ks] = *(const bf16x8*)(wcat + (size_t)n1 * KTOT + IN + ks * 32 + quad * 8);
    }

    const float bi  = bias[jcol];
    const float bfv = bias[256 + jcol];
    const float bg  = bias[512 + jcol];
    const float bo  = bias[768 + jcol];

    float cst[4], hn[4];
    {
        float cv = cx0[jcol];
        #pragma unroll
        for (int r = 0; r < 4; ++r) cst[r] = cv;
    }

    // ---- x[0] (consumed pre-loop) and x[1] (prefetch) ----
    float4 x0f[8], xf[8];
    #pragma unroll
    for (int ks = 0; ks < 4; ++ks) {
        const float* xp = x + (size_t)(b0 + col) * IN + ks * 32 + quad * 8;
        x0f[2 * ks]     = *(const float4*)xp;
        x0f[2 * ks + 1] = *(const float4*)(xp + 4);
        const float* xq = xp + (size_t)BATCH * IN;
        xf[2 * ks]      = *(const float4*)xq;
        xf[2 * ks + 1]  = *(const float4*)(xq + 4);
    }

    // ---- exchange-buffer pointers (per-lane, both parities) ----
    const __bf16* hb0 = hexg + (size_t)g * (BWG * HID) + col * HID + quad * 8;
    const __bf16* hb1 = hb0 + (size_t)NGROUP * (BWG * HID);
    unsigned *pb0, *pb1;
    {
        __bf16* pp = hexg + (size_t)g * (BWG * HID) + (size_t)(quad * 4) * HID + jcol;
        pb0 = (unsigned*)pp;
        pb1 = (unsigned*)(pp + (size_t)NGROUP * (BWG * HID));
    }
    const unsigned short* fpoll = flags + g * 32 + (lane & 31);
    unsigned short*       fmine = flags + g * 32 + s * 8 + wave;

    // ---- x-part for t=0 ----
    f32x4 aA0 = {0.f,0.f,0.f,0.f}, aA1 = {0.f,0.f,0.f,0.f};
    f32x4 aB0 = {0.f,0.f,0.f,0.f}, aB1 = {0.f,0.f,0.f,0.f};
    {
        bf16x8 ax[4];
        #pragma unroll
        for (int ks = 0; ks < 4; ++ks)
            ax[ks] = cvt_pack(x0f[2 * ks], x0f[2 * ks + 1]);
        aA0 = MFMA(ax[0], wi0[0], aA0); aB0 = MFMA(ax[0], wi1[0], aB0);
        aA1 = MFMA(ax[1], wi0[1], aA1); aB1 = MFMA(ax[1], wi1[1], aB1);
        aA0 = MFMA(ax[2], wi0[2], aA0); aB0 = MFMA(ax[2], wi1[2], aB0);
        aA1 = MFMA(ax[3], wi0[3], aA1); aB1 = MFMA(ax[3], wi1[3], aB1);
    }

    for (int t = 0; t < T_STEPS; ++t) {
        // ---- A: obtain h_t A-fragments ----
        bf16x8 ahf[8];
        if (t == 0) {
            #pragma unroll
            for (int ks = 0; ks < 8; ++ks) {
                const float* hp = hx0 + ks * 32 + quad * 8;
                ahf[ks] = cvt_pack(*(const float4*)hp, *(const float4*)(hp + 4));
            }
        } else {
            // poll the 32 per-wave slot flags (one coalesced 64B line)
            int guard = 0;
            for (;;) {
                unsigned fv = ld_u16_coh(fpoll);
                if (__all((int)fv >= t)) break;
                if (++guard > (1 << 16)) break;     // fail-fast over deadlock
                __builtin_amdgcn_s_sleep(1);
            }
            const __bf16* hbase = (t & 1) ? hb1 : hb0;
            ld_hfrag(ahf, hbase);                   // direct global -> frag
        }

        // ---- B: h-part MFMAs (register-resident weights) + cell ----
        #pragma unroll
        for (int ks = 0; ks < 4; ++ks) {
            aA0 = MFMA(ahf[ks],     wh0[ks],     aA0);
            aB0 = MFMA(ahf[ks],     wh1[ks],     aB0);
            aA1 = MFMA(ahf[ks + 4], wh0[ks + 4], aA1);
            aB1 = MFMA(ahf[ks + 4], wh1[ks + 4], aB1);
        }
        f32x4 accA = aA0 + aA1;   // i (hf=0) / f (hf=1)
        f32x4 accB = aB0 + aB1;   // g (hf=0) / o (hf=1)

        #pragma unroll
        for (int r = 0; r < 4; ++r) {
            float oA = __shfl_xor(accA[r], 8, 64);
            float oB = __shfl_xor(accB[r], 8, 64);
            float iv = (hf ? oA : accA[r]) + bi;
            float fv = (hf ? accA[r] : oA) + bfv;
            float gv = (hf ? oB : accB[r]) + bg;
            float ov = (hf ? accB[r] : oB) + bo;
            float ig = sigmoidf_fast(iv);
            float fg = sigmoidf_fast(fv);
            float gt = tanhf_fast(gv);
            float og = sigmoidf_fast(ov);
            float cn = fg * cst[r] + ig * gt;
            cst[r] = cn;
            hn[r]  = og * tanhf_fast(cn);
        }

        // ---- C: publish h_{t+1}, drain to coherence point, set slot flag ----
        if (t < T_STEPS - 1) {
            unsigned* pb = (t & 1) ? pb0 : pb1;      // buf (t+1)&1
            #pragma unroll
            for (int r = 0; r < 4; ++r) {
                unsigned short mine;
                {
                    __bf16 hv = (__bf16)hn[r];
                    __builtin_memcpy(&mine, &hv, 2);
                }
                int other = __shfl_xor((int)mine, 1, 64);
                if ((col & 1) == 0 && col < 8) {
                    unsigned val = (unsigned)mine
                                 | ((unsigned)(unsigned short)other << 16);
                    st_u32_coh(pb + r * 128, val);
                }
            }
            asm volatile("s_waitcnt vmcnt(0)" ::: "memory");
            if (lane == 0) st_u16_coh(fmine, (unsigned)(t + 1));

            // ---- D: x-part for t+1 in the handshake shadow ----
            {
                bf16x8 ax[4];
                #pragma unroll
                for (int ks = 0; ks < 4; ++ks)
                    ax[ks] = cvt_pack(xf[2 * ks], xf[2 * ks + 1]);
                aA0 = {0.f,0.f,0.f,0.f}; aA1 = {0.f,0.f,0.f,0.f};
                aB0 = {0.f,0.f,0.f,0.f}; aB1 = {0.f,0.f,0.f,0.f};
                aA0 = MFMA(ax[0], wi0[0], aA0); aB0 = MFMA(ax[0], wi1[0], aB0);
                aA1 = MFMA(ax[1], wi0[1], aA1); aB1 = MFMA(ax[1], wi1[1], aB1);
                aA0 = MFMA(ax[2], wi0[2], aA0); aB0 = MFMA(ax[2], wi1[2], aB0);
                aA1 = MFMA(ax[3], wi0[3], aA1); aB1 = MFMA(ax[3], wi1[3], aB1);
            }
            // prefetch x[t+2]
            if (t + 2 <= T_STEPS - 1) {
                #pragma unroll
                for (int ks = 0; ks < 4; ++ks) {
                    const float* xp = x + (size_t)(t + 2) * BATCH * IN
                                    + (size_t)(b0 + col) * IN + ks * 32 + quad * 8;
                    xf[2 * ks]     = *(const float4*)xp;
                    xf[2 * ks + 1] = *(const float4*)(xp + 4);
                }
            }
        }
    }

    // ---- final h, c ----
    if (col < 8) {
        #pragma unroll
        for (int r = 0; r < 4; ++r) {
            int row = b0 + quad * 4 + r;
            out[(size_t)row * HID + jcol] = hn[r];
            out[(size_t)BATCH * HID + (size_t)row * HID + jcol] = cst[r];
        }
    }
}

extern "C" void kernel_launch(void* const* d_in, const int* in_sizes, int n_in,
                              void* d_out, int out_size, void* d_ws, size_t ws_size,
                              hipStream_t stream) {
    const float* x    = (const float*)d_in[0];
    const float* W_ih = (const float*)d_in[1];
    const float* W_hh = (const float*)d_in[2];
    const float* b_ih = (const float*)d_in[3];
    const float* b_hh = (const float*)d_in[4];
    const float* hx0  = (const float*)d_in[5];
    const float* cx0  = (const float*)d_in[6];
    float* outp = (float*)d_out;

    __bf16* wcat = (__bf16*)((char*)d_ws + WCAT_OFF);
    float*  bias = (float*)((char*)d_ws + BIAS_OFF);
    __bf16* hexg = (__bf16*)((char*)d_ws + HEXG_OFF);
    int*    cnt  = (int*)((char*)d_ws + CNT_OFF);

    precast_kernel<<<dim3((NG * KTOT + 255) / 256), dim3(256), 0, stream>>>(
        W_ih, W_hh, b_ih, b_hh, wcat, bias, cnt);

    void* args[] = {(void*)&x, (void*)&wcat, (void*)&bias, (void*)&hx0,
                    (void*)&cx0, (void*)&hexg, (void*)&cnt, (void*)&outp};
    hipLaunchCooperativeKernel((const void*)lstm_kernel, dim3(256), dim3(512),
                               args, 0, stream);
}